// Round 10
// baseline (129.054 us; speedup 1.0000x reference)
//
#include <hip/hip_runtime.h>
#include <hip/hip_bf16.h>

#define B_SZ 8192
#define D_SZ 256
#define NTILES 2080    // (8192/128)*(8192/128+1)/2 upper-tri tiles
#define GRID_SIM 1040  // 2 tiles/block exactly; 2 blocks/CU resident, backfilled
#define SL 8192        // partial-slot stride (one float per row)
#define NSLOT 130      // row-side slots 0..127, col-side 128..129 per strip
// rows pre-scaled by sqrt(log2(e)/T): exp2(acc) == exp(sim/T)
#define PRESCALE 4.539816004686735f

typedef __attribute__((ext_vector_type(4))) float f32x4;
typedef __attribute__((ext_vector_type(8))) short s16x8;

// ---------------- L2-normalize rows, scale, cast to bf16 -------------------
__global__ __launch_bounds__(256) void norm_kernel(const float* __restrict__ emb,
                                                   ushort* __restrict__ nbf,
                                                   float* __restrict__ acc2) {
    if (blockIdx.x == 0 && threadIdx.x < 2) acc2[threadIdx.x] = 0.0f;  // loss,cnt

    const int wave = threadIdx.x >> 6, lane = threadIdx.x & 63;
    for (int g = blockIdx.x; g < B_SZ / 4; g += 256) {
        const int row = g * 4 + wave;
        const float4 v = ((const float4*)(emb + (size_t)row * D_SZ))[lane];
        float ss = v.x * v.x + v.y * v.y + v.z * v.z + v.w * v.w;
        #pragma unroll
        for (int m = 1; m < 64; m <<= 1) ss += __shfl_xor(ss, m, 64);
        float s = PRESCALE / fmaxf(sqrtf(ss), 1e-12f);
        __hip_bfloat16 b0 = __float2bfloat16(v.x * s);
        __hip_bfloat16 b1 = __float2bfloat16(v.y * s);
        __hip_bfloat16 b2 = __float2bfloat16(v.z * s);
        __hip_bfloat16 b3 = __float2bfloat16(v.w * s);
        ushort4 o;
        o.x = *(ushort*)&b0; o.y = *(ushort*)&b1; o.z = *(ushort*)&b2; o.w = *(ushort*)&b3;
        ((ushort4*)(nbf + (size_t)row * D_SZ))[lane] = o;
    }
}

// ---------------- helpers ---------------------------------------------------
__device__ __forceinline__ void decode_tile(int tb, int& i0, int& j0, bool& diag) {
    int bj = (int)((sqrtf(8.0f * tb + 1.0f) - 1.0f) * 0.5f);
    while ((bj + 1) * (bj + 2) / 2 <= tb) ++bj;
    while (bj * (bj + 1) / 2 > tb) --bj;
    const int bi = tb - bj * (bj + 1) / 2;
    i0 = bi * 128; j0 = bj * 128; diag = (bi == bj);
}

// async global->LDS DMA, 16 B per lane. LDS dest = wave-uniform base +
// lane*16 (linear); swizzle lives in the per-lane GLOBAL address (c8s).
__device__ __forceinline__ void gload16(const ushort* g, ushort* l) {
    __builtin_amdgcn_global_load_lds(
        (const __attribute__((address_space(1))) unsigned int*)g,
        (__attribute__((address_space(3))) unsigned int*)l,
        16, 0, 0);
}

// Issue one k64-stage of A+B staging as 8 DMAs per wave (verified pattern).
__device__ __forceinline__ void issue_stage(ushort* bA,
                                            const ushort* __restrict__ N,
                                            int i0, int j0, int k0,
                                            int wave, int r, int c8s) {
    ushort* bB = bA + 8192;
    const ushort* gA = N + (size_t)(i0 + wave * 32) * D_SZ + k0;
    const ushort* gB = N + (size_t)(j0 + wave * 32) * D_SZ + k0;
    #pragma unroll
    for (int q = 0; q < 4; ++q) {
        gload16(gA + (size_t)(q * 8 + r) * D_SZ + c8s, bA + (wave * 32 + q * 8) * 64);
        gload16(gB + (size_t)(q * 8 + r) * D_SZ + c8s, bB + (wave * 32 + q * 8) * 64);
    }
}

// ---------------- fused sim: DMA pipeline (R3-verified) + slot-store epilogue
// Per stage: vmcnt(0) [stage-k DMAs landed] -> barrier -> issue DMA k+1 into
// other buffer -> ds_read + MFMA. 4 barriers/tile, NO epilogue barriers, NO
// atomics: each (tile,wave) owns disjoint global partial slots.
//   row-side slot  = 2*(bj-bi)+wx   (strip bi)
//   col-side slot  = 129-2*bi-wy    (strip bj; diag tiles write zeros)
// Together they cover [0,129] exactly once per row -> no zeroing, no RMW.
__global__ __launch_bounds__(256) void sim_kernel(const ushort* __restrict__ N,
                                                  const int* __restrict__ ids,
                                                  float* __restrict__ allP,
                                                  float* __restrict__ posP) {
    __shared__ ushort smem[4 * 128 * 64];   // A0|B0|A1|B1, 16 KB each

    const int t    = threadIdx.x;
    const int wave = t >> 6, lane = t & 63;
    const int wy   = wave >> 1, wx = wave & 1;
    const int r    = lane >> 3;                     // 0..7 sub-row
    const int c8s  = ((lane & 7) ^ r) * 8;          // swizzled source chunk
    const int hi   = lane >> 4, myc = lane & 15;

    int tb = blockIdx.x;
    int i0, j0; bool diag;
    decode_tile(tb, i0, j0, diag);

    issue_stage(smem, N, i0, j0, 0, wave, r, c8s);  // prologue: stage 0 -> buf0

    while (true) {
        const int ntb = tb + GRID_SIM;
        const bool have_next = (ntb < NTILES);
        int ni0 = i0, nj0 = j0; bool ndiag = diag;
        if (have_next) decode_tile(ntb, ni0, nj0, ndiag);

        f32x4 acc[4][4];
        #pragma unroll
        for (int mi = 0; mi < 4; ++mi)
            #pragma unroll
            for (int ni = 0; ni < 4; ++ni)
                acc[mi][ni] = (f32x4){0.f, 0.f, 0.f, 0.f};

        #pragma unroll
        for (int kk = 0; kk < 4; ++kk) {
            ushort* bA = smem + (kk & 1) * 16384;          // read buffer
            ushort* bW = smem + ((kk + 1) & 1) * 16384;    // write buffer
            ushort* bB = bA + 8192;

            asm volatile("s_waitcnt vmcnt(0)" ::: "memory");  // stage-k DMAs landed
            __syncthreads();
            if (kk < 3)           issue_stage(bW, N, i0, j0, (kk + 1) * 64, wave, r, c8s);
            else if (have_next)   issue_stage(bW, N, ni0, nj0, 0, wave, r, c8s);

            #pragma unroll
            for (int ks = 0; ks < 2; ++ks) {
                const int C = ks * 4 + hi;              // k-chunk index 0..7
                const int slot = (C ^ (lane & 7)) * 8;  // un-swizzle
                s16x8 af[4], bf[4];
                #pragma unroll
                for (int mi = 0; mi < 4; ++mi)
                    af[mi] = *(const s16x8*)&bA[(wy * 64 + mi * 16 + myc) * 64 + slot];
                #pragma unroll
                for (int ni = 0; ni < 4; ++ni)
                    bf[ni] = *(const s16x8*)&bB[(wx * 64 + ni * 16 + myc) * 64 + slot];
                #pragma unroll
                for (int mi = 0; mi < 4; ++mi)
                    #pragma unroll
                    for (int ni = 0; ni < 4; ++ni)
                        acc[mi][ni] = __builtin_amdgcn_mfma_f32_16x16x32_bf16(
                            af[mi], bf[ni], acc[mi][ni], 0, 0, 0);
            }
        }

        // ---- epilogue: registers + plain slot stores (no LDS, no atomics).
        // C/D map: col=lane&15, row=hi*4+reg
        const int bi = i0 >> 7, bj = j0 >> 7;
        const int slotR = 2 * (bj - bi) + wx;
        const int slotC = 129 - 2 * bi - wy;

        int idc[4];
        #pragma unroll
        for (int ni = 0; ni < 4; ++ni)
            idc[ni] = ids[j0 + wx * 64 + ni * 16 + myc];

        float cAll[4] = {0.f, 0.f, 0.f, 0.f};
        float cPos[4] = {0.f, 0.f, 0.f, 0.f};

        #pragma unroll
        for (int mi = 0; mi < 4; ++mi) {
            float rAll[4] = {0.f, 0.f, 0.f, 0.f};
            float rPos[4] = {0.f, 0.f, 0.f, 0.f};
            const int rbase = wy * 64 + mi * 16 + hi * 4;   // local row base
            const int4 idr  = *(const int4*)&ids[i0 + rbase];
            #pragma unroll
            for (int ni = 0; ni < 4; ++ni) {
                const int cloc = wx * 64 + ni * 16 + myc;   // local col
                #pragma unroll
                for (int rg = 0; rg < 4; ++rg) {
                    float e = __builtin_amdgcn_exp2f(acc[mi][ni][rg]);
                    if (diag && (rbase + rg) == cloc) e = 0.0f;   // diagonal
                    rAll[rg] += e; cAll[ni] += e;
                    const int idrv = (rg == 0) ? idr.x : (rg == 1) ? idr.y
                                   : (rg == 2) ? idr.z : idr.w;
                    if (idrv == idc[ni]) { rPos[rg] += e; cPos[ni] += e; }
                }
            }
            // sum the wave's 16-col slice: 4-step butterfly within hi-group
            #pragma unroll
            for (int rg = 0; rg < 4; ++rg) {
                #pragma unroll
                for (int m = 1; m < 16; m <<= 1) {
                    rAll[rg] += __shfl_xor(rAll[rg], m, 64);
                    rPos[rg] += __shfl_xor(rPos[rg], m, 64);
                }
            }
            if (myc == 0) {     // lanes 0,16,32,48: rows rbase..rbase+3
                float4 sa = {rAll[0], rAll[1], rAll[2], rAll[3]};
                float4 sp = {rPos[0], rPos[1], rPos[2], rPos[3]};
                *(float4*)&allP[(size_t)slotR * SL + i0 + rbase] = sa;
                *(float4*)&posP[(size_t)slotR * SL + i0 + rbase] = sp;
            }
        }

        // col sums -> symmetric partials for strip bj (zeros on diag tiles)
        #pragma unroll
        for (int ni = 0; ni < 4; ++ni) {
            cAll[ni] += __shfl_xor(cAll[ni], 16, 64);
            cAll[ni] += __shfl_xor(cAll[ni], 32, 64);
            cPos[ni] += __shfl_xor(cPos[ni], 16, 64);
            cPos[ni] += __shfl_xor(cPos[ni], 32, 64);
        }
        if (lane < 16) {
            #pragma unroll
            for (int ni = 0; ni < 4; ++ni) {
                const int gc = j0 + wx * 64 + ni * 16 + lane;
                allP[(size_t)slotC * SL + gc] = diag ? 0.0f : cAll[ni];
                posP[(size_t)slotC * SL + gc] = diag ? 0.0f : cPos[ni];
            }
        }
        // No barrier: epilogue touched no LDS; next tile's vmcnt(0)+barrier
        // orders the buf1 DMA writes vs this tile's kk=3 reads.

        if (!have_next) break;
        tb = ntb; i0 = ni0; j0 = nj0; diag = ndiag;
    }
}

// ---------------- per-row partial fold + loss accumulate -------------------
__global__ __launch_bounds__(256) void reduce_kernel(const float* __restrict__ allP,
                                                     const float* __restrict__ posP,
                                                     float* __restrict__ acc2) {
    const int row = blockIdx.x * 256 + threadIdx.x;   // grid 32 -> 8192 rows
    float a = 0.0f, p = 0.0f;
    for (int s = 0; s < NSLOT; ++s) {                 // coalesced: stride SL
        a += allP[(size_t)s * SL + row];
        p += posP[(size_t)s * SL + row];
    }
    float loss = 0.0f, cnt = 0.0f;
    if (p > 0.0f) { loss = logf(a) - logf(p); cnt = 1.0f; }
    #pragma unroll
    for (int m = 1; m < 64; m <<= 1) {
        loss += __shfl_xor(loss, m, 64);
        cnt  += __shfl_xor(cnt, m, 64);
    }
    __shared__ float sl[4], sc[4];
    const int wave = threadIdx.x >> 6, lane = threadIdx.x & 63;
    if (lane == 0) { sl[wave] = loss; sc[wave] = cnt; }
    __syncthreads();
    if (threadIdx.x == 0) {
        atomicAdd(&acc2[0], sl[0] + sl[1] + sl[2] + sl[3]);
        atomicAdd(&acc2[1], sc[0] + sc[1] + sc[2] + sc[3]);
    }
}

__global__ void final_kernel(const float* __restrict__ acc2, float* __restrict__ out) {
    out[0] = acc2[0] / fmaxf(acc2[1], 1.0f);
}

extern "C" void kernel_launch(void* const* d_in, const int* in_sizes, int n_in,
                              void* d_out, int out_size, void* d_ws, size_t ws_size,
                              hipStream_t stream) {
    const float* emb = (const float*)d_in[0];
    const int*   ids = (const int*)d_in[1];
    float*       out = (float*)d_out;

    float*  acc2 = (float*)d_ws;                                // [loss, cnt]
    float*  allP = (float*)((char*)d_ws + 4096);                // 130*8192 f32
    float*  posP = allP + (size_t)NSLOT * SL;                   // 130*8192 f32
    ushort* nbf  = (ushort*)(posP + (size_t)NSLOT * SL);        // 4 MB bf16

    norm_kernel<<<256, 256, 0, stream>>>(emb, nbf, acc2);
    sim_kernel<<<GRID_SIM, 256, 0, stream>>>(nbf, ids, allP, posP);
    reduce_kernel<<<32, 256, 0, stream>>>(allP, posP, acc2);
    final_kernel<<<1, 1, 0, stream>>>(acc2, out);
}

// Round 11
// 126.371 us; speedup vs baseline: 1.0212x; 1.0212x over previous
//
#include <hip/hip_runtime.h>
#include <hip/hip_bf16.h>

#define B_SZ 8192
#define D_SZ 256
#define NTILES 2080    // (8192/128)*(8192/128+1)/2 upper-tri tiles
#define GRID_SIM 512   // persistent, 2 blocks/CU, 4-5 tiles/block (R3 schedule)
#define SL 8192        // partial-slot stride (one float per row)
#define NSLOT 130      // row-side slots 0..127, col-side 128..129 per strip
// rows pre-scaled by sqrt(log2(e)/T): exp2(acc) == exp(sim/T)
#define PRESCALE 4.539816004686735f

typedef __attribute__((ext_vector_type(4))) float f32x4;
typedef __attribute__((ext_vector_type(8))) short s16x8;

// ---------------- L2-normalize rows, scale, cast to bf16 -------------------
__global__ __launch_bounds__(256) void norm_kernel(const float* __restrict__ emb,
                                                   ushort* __restrict__ nbf,
                                                   float* __restrict__ acc2) {
    if (blockIdx.x == 0 && threadIdx.x < 2) acc2[threadIdx.x] = 0.0f;  // loss,cnt

    const int wave = threadIdx.x >> 6, lane = threadIdx.x & 63;
    for (int g = blockIdx.x; g < B_SZ / 4; g += 256) {
        const int row = g * 4 + wave;
        const float4 v = ((const float4*)(emb + (size_t)row * D_SZ))[lane];
        float ss = v.x * v.x + v.y * v.y + v.z * v.z + v.w * v.w;
        #pragma unroll
        for (int m = 1; m < 64; m <<= 1) ss += __shfl_xor(ss, m, 64);
        float s = PRESCALE / fmaxf(sqrtf(ss), 1e-12f);
        __hip_bfloat16 b0 = __float2bfloat16(v.x * s);
        __hip_bfloat16 b1 = __float2bfloat16(v.y * s);
        __hip_bfloat16 b2 = __float2bfloat16(v.z * s);
        __hip_bfloat16 b3 = __float2bfloat16(v.w * s);
        ushort4 o;
        o.x = *(ushort*)&b0; o.y = *(ushort*)&b1; o.z = *(ushort*)&b2; o.w = *(ushort*)&b3;
        ((ushort4*)(nbf + (size_t)row * D_SZ))[lane] = o;
    }
}

// ---------------- helpers ---------------------------------------------------
__device__ __forceinline__ void decode_tile(int tb, int& i0, int& j0, bool& diag) {
    int bj = (int)((sqrtf(8.0f * tb + 1.0f) - 1.0f) * 0.5f);
    while ((bj + 1) * (bj + 2) / 2 <= tb) ++bj;
    while (bj * (bj + 1) / 2 > tb) --bj;
    const int bi = tb - bj * (bj + 1) / 2;
    i0 = bi * 128; j0 = bj * 128; diag = (bi == bj);
}

// async global->LDS DMA, 16 B per lane. LDS dest = wave-uniform base +
// lane*16 (linear); swizzle lives in the per-lane GLOBAL address (c8s).
__device__ __forceinline__ void gload16(const ushort* g, ushort* l) {
    __builtin_amdgcn_global_load_lds(
        (const __attribute__((address_space(1))) unsigned int*)g,
        (__attribute__((address_space(3))) unsigned int*)l,
        16, 0, 0);
}

// Issue one k64-stage of A+B staging as 8 DMAs per wave (verified pattern).
__device__ __forceinline__ void issue_stage(ushort* bA,
                                            const ushort* __restrict__ N,
                                            int i0, int j0, int k0,
                                            int wave, int r, int c8s) {
    ushort* bB = bA + 8192;
    const ushort* gA = N + (size_t)(i0 + wave * 32) * D_SZ + k0;
    const ushort* gB = N + (size_t)(j0 + wave * 32) * D_SZ + k0;
    #pragma unroll
    for (int q = 0; q < 4; ++q) {
        gload16(gA + (size_t)(q * 8 + r) * D_SZ + c8s, bA + (wave * 32 + q * 8) * 64);
        gload16(gB + (size_t)(q * 8 + r) * D_SZ + c8s, bB + (wave * 32 + q * 8) * 64);
    }
}

// ---------------- fused sim: DMA pipeline (R3-verified) + slot-store epilogue
// Per stage: vmcnt(0) [stage-k DMAs landed] -> barrier -> issue DMA k+1 into
// other buffer -> ds_read + MFMA. 4 barriers/tile, NO epilogue barriers, NO
// atomics: each (tile,wave) owns disjoint global partial slots.
//   row-side slot  = 2*(bj-bi)+wx   (strip bi)
//   col-side slot  = 129-2*bi-wy    (strip bj; diag tiles write zeros)
// Together they cover [0,129] exactly once per row -> no zeroing, no RMW.
__global__ __launch_bounds__(256) void sim_kernel(const ushort* __restrict__ N,
                                                  const int* __restrict__ ids,
                                                  float* __restrict__ allP,
                                                  float* __restrict__ posP) {
    __shared__ ushort smem[4 * 128 * 64];   // A0|B0|A1|B1, 16 KB each

    const int t    = threadIdx.x;
    const int wave = t >> 6, lane = t & 63;
    const int wy   = wave >> 1, wx = wave & 1;
    const int r    = lane >> 3;                     // 0..7 sub-row
    const int c8s  = ((lane & 7) ^ r) * 8;          // swizzled source chunk
    const int hi   = lane >> 4, myc = lane & 15;

    int tb = blockIdx.x;
    int i0, j0; bool diag;
    decode_tile(tb, i0, j0, diag);

    issue_stage(smem, N, i0, j0, 0, wave, r, c8s);  // prologue: stage 0 -> buf0

    while (true) {
        const int ntb = tb + GRID_SIM;
        const bool have_next = (ntb < NTILES);
        int ni0 = i0, nj0 = j0; bool ndiag = diag;
        if (have_next) decode_tile(ntb, ni0, nj0, ndiag);

        f32x4 acc[4][4];
        #pragma unroll
        for (int mi = 0; mi < 4; ++mi)
            #pragma unroll
            for (int ni = 0; ni < 4; ++ni)
                acc[mi][ni] = (f32x4){0.f, 0.f, 0.f, 0.f};

        #pragma unroll
        for (int kk = 0; kk < 4; ++kk) {
            ushort* bA = smem + (kk & 1) * 16384;          // read buffer
            ushort* bW = smem + ((kk + 1) & 1) * 16384;    // write buffer
            ushort* bB = bA + 8192;

            asm volatile("s_waitcnt vmcnt(0)" ::: "memory");  // stage-k DMAs landed
            __syncthreads();
            if (kk < 3)           issue_stage(bW, N, i0, j0, (kk + 1) * 64, wave, r, c8s);
            else if (have_next)   issue_stage(bW, N, ni0, nj0, 0, wave, r, c8s);

            #pragma unroll
            for (int ks = 0; ks < 2; ++ks) {
                const int C = ks * 4 + hi;              // k-chunk index 0..7
                const int slot = (C ^ (lane & 7)) * 8;  // un-swizzle
                s16x8 af[4], bf[4];
                #pragma unroll
                for (int mi = 0; mi < 4; ++mi)
                    af[mi] = *(const s16x8*)&bA[(wy * 64 + mi * 16 + myc) * 64 + slot];
                #pragma unroll
                for (int ni = 0; ni < 4; ++ni)
                    bf[ni] = *(const s16x8*)&bB[(wx * 64 + ni * 16 + myc) * 64 + slot];
                #pragma unroll
                for (int mi = 0; mi < 4; ++mi)
                    #pragma unroll
                    for (int ni = 0; ni < 4; ++ni)
                        acc[mi][ni] = __builtin_amdgcn_mfma_f32_16x16x32_bf16(
                            af[mi], bf[ni], acc[mi][ni], 0, 0, 0);
            }
        }

        // ---- epilogue: registers + plain slot stores (no LDS, no atomics).
        // C/D map: col=lane&15, row=hi*4+reg
        const int bi = i0 >> 7, bj = j0 >> 7;
        const int slotR = 2 * (bj - bi) + wx;
        const int slotC = 129 - 2 * bi - wy;

        int idc[4];
        #pragma unroll
        for (int ni = 0; ni < 4; ++ni)
            idc[ni] = ids[j0 + wx * 64 + ni * 16 + myc];

        float cAll[4] = {0.f, 0.f, 0.f, 0.f};
        float cPos[4] = {0.f, 0.f, 0.f, 0.f};

        #pragma unroll
        for (int mi = 0; mi < 4; ++mi) {
            float rAll[4] = {0.f, 0.f, 0.f, 0.f};
            float rPos[4] = {0.f, 0.f, 0.f, 0.f};
            const int rbase = wy * 64 + mi * 16 + hi * 4;   // local row base
            const int4 idr  = *(const int4*)&ids[i0 + rbase];
            #pragma unroll
            for (int ni = 0; ni < 4; ++ni) {
                const int cloc = wx * 64 + ni * 16 + myc;   // local col
                #pragma unroll
                for (int rg = 0; rg < 4; ++rg) {
                    float e = __builtin_amdgcn_exp2f(acc[mi][ni][rg]);
                    if (diag && (rbase + rg) == cloc) e = 0.0f;   // diagonal
                    rAll[rg] += e; cAll[ni] += e;
                    const int idrv = (rg == 0) ? idr.x : (rg == 1) ? idr.y
                                   : (rg == 2) ? idr.z : idr.w;
                    if (idrv == idc[ni]) { rPos[rg] += e; cPos[ni] += e; }
                }
            }
            // sum the wave's 16-col slice: 4-step butterfly within hi-group
            #pragma unroll
            for (int rg = 0; rg < 4; ++rg) {
                #pragma unroll
                for (int m = 1; m < 16; m <<= 1) {
                    rAll[rg] += __shfl_xor(rAll[rg], m, 64);
                    rPos[rg] += __shfl_xor(rPos[rg], m, 64);
                }
            }
            if (myc == 0) {     // lanes 0,16,32,48: rows rbase..rbase+3
                float4 sa = {rAll[0], rAll[1], rAll[2], rAll[3]};
                float4 sp = {rPos[0], rPos[1], rPos[2], rPos[3]};
                *(float4*)&allP[(size_t)slotR * SL + i0 + rbase] = sa;
                *(float4*)&posP[(size_t)slotR * SL + i0 + rbase] = sp;
            }
        }

        // col sums -> symmetric partials for strip bj (zeros on diag tiles)
        #pragma unroll
        for (int ni = 0; ni < 4; ++ni) {
            cAll[ni] += __shfl_xor(cAll[ni], 16, 64);
            cAll[ni] += __shfl_xor(cAll[ni], 32, 64);
            cPos[ni] += __shfl_xor(cPos[ni], 16, 64);
            cPos[ni] += __shfl_xor(cPos[ni], 32, 64);
        }
        if (lane < 16) {
            #pragma unroll
            for (int ni = 0; ni < 4; ++ni) {
                const int gc = j0 + wx * 64 + ni * 16 + lane;
                allP[(size_t)slotC * SL + gc] = diag ? 0.0f : cAll[ni];
                posP[(size_t)slotC * SL + gc] = diag ? 0.0f : cPos[ni];
            }
        }
        // No barrier: epilogue touched no LDS; next tile's vmcnt(0)+barrier
        // orders the buf1 DMA writes vs this tile's kk=3 reads.

        if (!have_next) break;
        tb = ntb; i0 = ni0; j0 = nj0; diag = ndiag;
    }
}

// ---------------- per-row partial fold + loss accumulate -------------------
__global__ __launch_bounds__(256) void reduce_kernel(const float* __restrict__ allP,
                                                     const float* __restrict__ posP,
                                                     float* __restrict__ acc2) {
    const int row = blockIdx.x * 256 + threadIdx.x;   // grid 32 -> 8192 rows
    float a = 0.0f, p = 0.0f;
    for (int s = 0; s < NSLOT; ++s) {                 // coalesced: stride SL
        a += allP[(size_t)s * SL + row];
        p += posP[(size_t)s * SL + row];
    }
    float loss = 0.0f, cnt = 0.0f;
    if (p > 0.0f) { loss = logf(a) - logf(p); cnt = 1.0f; }
    #pragma unroll
    for (int m = 1; m < 64; m <<= 1) {
        loss += __shfl_xor(loss, m, 64);
        cnt  += __shfl_xor(cnt, m, 64);
    }
    __shared__ float sl[4], sc[4];
    const int wave = threadIdx.x >> 6, lane = threadIdx.x & 63;
    if (lane == 0) { sl[wave] = loss; sc[wave] = cnt; }
    __syncthreads();
    if (threadIdx.x == 0) {
        atomicAdd(&acc2[0], sl[0] + sl[1] + sl[2] + sl[3]);
        atomicAdd(&acc2[1], sc[0] + sc[1] + sc[2] + sc[3]);
    }
}

__global__ void final_kernel(const float* __restrict__ acc2, float* __restrict__ out) {
    out[0] = acc2[0] / fmaxf(acc2[1], 1.0f);
}

extern "C" void kernel_launch(void* const* d_in, const int* in_sizes, int n_in,
                              void* d_out, int out_size, void* d_ws, size_t ws_size,
                              hipStream_t stream) {
    const float* emb = (const float*)d_in[0];
    const int*   ids = (const int*)d_in[1];
    float*       out = (float*)d_out;

    float*  acc2 = (float*)d_ws;                                // [loss, cnt]
    float*  allP = (float*)((char*)d_ws + 4096);                // 130*8192 f32
    float*  posP = allP + (size_t)NSLOT * SL;                   // 130*8192 f32
    ushort* nbf  = (ushort*)(posP + (size_t)NSLOT * SL);        // 4 MB bf16

    norm_kernel<<<256, 256, 0, stream>>>(emb, nbf, acc2);
    sim_kernel<<<GRID_SIM, 256, 0, stream>>>(nbf, ids, allP, posP);
    reduce_kernel<<<32, 256, 0, stream>>>(allP, posP, acc2);
    final_kernel<<<1, 1, 0, stream>>>(acc2, out);
}